// Round 1
// baseline (977.429 us; speedup 1.0000x reference)
//
#include <hip/hip_runtime.h>
#include <hip/hip_bf16.h>

// CrossConv2d via bf16 MFMA implicit GEMM, u-reuse restructure.
// out[(b,s),co,h,w] = relu( BN(conv3x3(xy)) + xy ),  xy = concat(u[b], v[b,s])
// Key: conv = conv_u(u[b]) + conv_v(v[b,s]); the u-half is identical for all 8 s.
// One block = one (b, 16x16 tile); accumulate accU once, then loop s accumulating accV.
// MFMA operand swap: A = pixels (M=w), B = weights (N=co) -> lane holds 4 consecutive w
// in D -> float4 skip-load + float4 store in the epilogue.
// Double-buffered LDS staging with async split: load->regs, MFMA, cvt+ds_write, barrier.

#define EPS 1e-5f

typedef __attribute__((ext_vector_type(8))) short short8;   // 8 bf16 = 4 VGPRs
typedef __attribute__((ext_vector_type(4))) float f32x4;
typedef __attribute__((ext_vector_type(2))) float f32x2;

constexpr int C1 = 64, CC = 128, Hd = 128, Wd = 128;
constexpr int HW = Hd * Wd;          // 16384
constexpr int SP = 18;               // halo tile side (16 + 2)
constexpr int ROW = 40;              // ushorts per spatial point: 32 ci + 8 pad (80B, 16B-aligned)
constexpr int WFRAGS = 9 * 4 * 8;    // (t, ci-chunk, co-frag)
constexpr int NCHUNK = 18;           // u0,u1, then {v0,v1} x 8 s
constexpr int UNITS = 16 * 18 * 10;  // ci-pair x sph x float2-col units per chunk = 2880
constexpr int NTHR = 512;
constexpr int NU = (UNITS + NTHR - 1) / NTHR;   // 6

// ---- prep: fp32 OIHW weights -> bf16 B-fragments in ws (layout unchanged) ----
// frag f = (t*4 + c)*8 + cf ; lane l holds 8 bf16: co = cf*16+(l&15), ci = c*32+(l>>4)*8+j
__global__ void prep_weights(const float* __restrict__ wgt, ushort* __restrict__ wf) {
    int idx = blockIdx.x * 256 + threadIdx.x;
    if (idx >= WFRAGS * 64) return;
    int l  = idx & 63;
    int f  = idx >> 6;
    int cf = f & 7;
    int c  = (f >> 3) & 3;
    int t  = f >> 5;
    int kh = t / 3, kw = t % 3;
    int co  = cf * 16 + (l & 15);
    int cib = c * 32 + (l >> 4) * 8;
    ushort* dst = wf + (size_t)idx * 8;
#pragma unroll
    for (int j = 0; j < 8; ++j) {
        float x = wgt[(((size_t)co * CC + cib + j) * 3 + kh) * 3 + kw];
        __hip_bfloat16 bb = __float2bfloat16(x);
        dst[j] = *(ushort*)&bb;
    }
}

// ---- main: one block = one (b, 16x16 tile), loops s=0..7; 8 waves x 2 rows ----
__global__ __launch_bounds__(NTHR, 2)
void crossconv_mfma(const float* __restrict__ u,
                    const float* __restrict__ v,
                    const ushort* __restrict__ wf,
                    const float* __restrict__ gamma,
                    const float* __restrict__ beta,
                    const float* __restrict__ mean,
                    const float* __restrict__ var,
                    float* __restrict__ out) {
    __shared__ alignas(16) ushort in_s[2][SP * SP * ROW];   // 2 x 25920 B
    __shared__ float s_sc[CC], s_sh[CC];

    const int tid = threadIdx.x;
    const int w0 = blockIdx.x * 16;
    const int h0 = blockIdx.y * 16;
    const int b  = blockIdx.z;
    const float* __restrict__ ubase = u + (size_t)b * C1 * HW;
    const float* __restrict__ vbase = v + (size_t)b * 8 * C1 * HW;

    if (tid < CC) {
        float sc = gamma[tid] * rsqrtf(var[tid] + EPS);
        s_sc[tid] = sc;
        s_sh[tid] = beta[tid] - mean[tid] * sc;
    }
    // zero both staging buffers once: halo/OOB slots are OOB for EVERY chunk and
    // are simply never rewritten, so they stay zero for the whole kernel.
    {
        uint4 z{0u, 0u, 0u, 0u};
        uint4* p = (uint4*)&in_s[0][0];
        for (int i = tid; i < 2 * SP * SP * ROW / 8; i += NTHR) p[i] = z;
    }

    const int l = tid & 63, wid = tid >> 6;     // wave wid owns tile rows 2*wid, 2*wid+1
    const int n16 = l & 15, kgrp = l >> 4;

    f32x4 accU[8][2], accV[8][2];
#pragma unroll
    for (int cf = 0; cf < 8; ++cf) {
        accU[cf][0] = (f32x4)0.f; accU[cf][1] = (f32x4)0.f;
    }

    // staging registers (held in-flight across the MFMA phase: T14 async split)
    f32x2 sa[NU], sb[NU];
    int   sidx[NU];
    uint  sm0 = 0, sm1 = 0;

    auto chunk_src = [&](int k) -> const float* {
        if (k < 2) return ubase + (size_t)k * 32 * HW;            // u chunks: ci 0..31 / 32..63
        int km = k - 2;                                           // v chunks of s = km>>1
        return vbase + ((size_t)(km >> 1) * C1 + (size_t)(km & 1) * 32) * HW;
    };

    // issue global loads for a chunk into registers (no LDS traffic yet)
    auto stage_load = [&](const float* __restrict__ src) {
        sm0 = sm1 = 0;
#pragma unroll
        for (int i = 0; i < NU; ++i) {
            int e = tid + i * NTHR;
            sa[i] = f32x2{0.f, 0.f}; sb[i] = f32x2{0.f, 0.f}; sidx[i] = 0;
            if (e < UNITS) {
                int cp  = e / 180;          // ci pair 0..15
                int r   = e - cp * 180;
                int sph = r / 10;           // halo row 0..17
                int j   = r - sph * 10;     // float2 column unit 0..9
                int gh  = h0 + sph - 1;
                int gw  = w0 + 2 * j - 2;   // even -> 8B-aligned float2
                sidx[i] = (sph * SP + 2 * j) * ROW + 2 * cp;
                // load iff both columns in-image; all slots this guard skips are
                // genuinely zero-padded halo (stay pre-zeroed).
                if ((unsigned)gh < (unsigned)Hd && (unsigned)gw < (unsigned)(Wd - 1)) {
                    const float* p = src + (size_t)(2 * cp) * HW + gh * Wd + gw;
                    sa[i] = *(const f32x2*)p;          // ci = 2cp
                    sb[i] = *(const f32x2*)(p + HW);   // ci = 2cp+1
                    if (j >= 1) sm0 |= 1u << i;        // spw = 2j-1 valid
                    if (j <= 8) sm1 |= 1u << i;        // spw = 2j   valid
                }
            }
        }
    };

    // convert + packed b32 LDS writes (ci pair adjacent in [point][ci] layout)
    auto stage_write = [&](int buf) {
        ushort* __restrict__ d = in_s[buf];
#pragma unroll
        for (int i = 0; i < NU; ++i) {
            __hip_bfloat16 ax = __float2bfloat16(sa[i].x);
            __hip_bfloat16 bx = __float2bfloat16(sb[i].x);
            __hip_bfloat16 ay = __float2bfloat16(sa[i].y);
            __hip_bfloat16 by = __float2bfloat16(sb[i].y);
            uint v0 = (uint)*(ushort*)&ax | ((uint)*(ushort*)&bx << 16);
            uint v1 = (uint)*(ushort*)&ay | ((uint)*(ushort*)&by << 16);
            if (sm0 & (1u << i)) *(uint*)&d[sidx[i] - ROW] = v0;
            if (sm1 & (1u << i)) *(uint*)&d[sidx[i]]       = v1;
        }
    };

    // MFMA on one staged 32-ci chunk. A = pixels (M=w), B = weights (N=co):
    // identical lane maps to before, swapped operands -> D rows are w.
    auto compute = [&](int buf, int c, f32x4 (&acc)[8][2]) {
        const ushort* __restrict__ bs = in_s[buf];
#pragma unroll
        for (int t = 0; t < 9; ++t) {
            const int kh = t / 3, kw = t % 3;
            const int spw = n16 + kw;
            short8 p0 = *(const short8*)&bs[((wid * 2 + 0 + kh) * SP + spw) * ROW + kgrp * 8];
            short8 p1 = *(const short8*)&bs[((wid * 2 + 1 + kh) * SP + spw) * ROW + kgrp * 8];
            const short8* __restrict__ wp =
                (const short8*)wf + ((size_t)(t * 4 + c) * 8) * 64 + l;
#pragma unroll
            for (int cf = 0; cf < 8; ++cf) {
                short8 wfr = wp[(size_t)cf * 64];        // L2-resident, 1KB/wave
                acc[cf][0] = __builtin_amdgcn_mfma_f32_16x16x32_bf16(p0, wfr, acc[cf][0], 0, 0, 0);
                acc[cf][1] = __builtin_amdgcn_mfma_f32_16x16x32_bf16(p1, wfr, acc[cf][1], 0, 0, 0);
            }
        }
    };

    __syncthreads();                 // zero-fill + BN table visible to all waves
    stage_load(chunk_src(0));
    stage_write(0);
    __syncthreads();

    for (int k = 0; k < NCHUNK; ++k) {
        const int cur = k & 1;
        if (k + 1 < NCHUNK) stage_load(chunk_src(k + 1));   // loads fly under MFMA
        if (k >= 2 && (k & 1) == 0) {                       // start of an s: seed accV
#pragma unroll
            for (int cf = 0; cf < 8; ++cf) {
                accV[cf][0] = accU[cf][0]; accV[cf][1] = accU[cf][1];
            }
        }
        const int c = (k < 2) ? k : 2 + ((k - 2) & 1);      // weight ci-chunk index
        if (k < 2) compute(cur, c, accU);                   // branch (not ptr select):
        else       compute(cur, c, accV);                   // keeps acc arrays in regs
        if (k + 1 < NCHUNK) stage_write(cur ^ 1);
        if (k >= 3 && (k & 1)) {
            // ---- epilogue for s = (k-3)/2: BN + fp32 skip + ReLU, float4 I/O ----
            const int s = (k - 3) >> 1;
            const size_t n = (size_t)b * 8 + s;
#pragma unroll
            for (int cf = 0; cf < 8; ++cf) {
                const int co = cf * 16 + n16;               // D col = co
                const float sc = s_sc[co], sh = s_sh[co];
                const float* __restrict__ xb = (cf < 4)
                    ? (ubase + (size_t)co * HW)
                    : (vbase + ((size_t)s * C1 + (co - C1)) * HW);
                float* __restrict__ ob = out + ((size_t)n * CC + co) * HW;
#pragma unroll
                for (int pf = 0; pf < 2; ++pf) {
                    const int off = (h0 + wid * 2 + pf) * Wd + w0 + kgrp * 4;  // 4 consec w
                    f32x4 x = *(const f32x4*)(xb + off);
                    f32x4 a = accV[cf][pf];
                    f32x4 y;
#pragma unroll
                    for (int r = 0; r < 4; ++r)
                        y[r] = fmaxf(fmaf(a[r], sc, sh) + x[r], 0.f);
                    *(f32x4*)(ob + off) = y;
                }
            }
        }
        __syncthreads();            // staged chunk k+1 ready; buffer k free for k+2
    }
}

extern "C" void kernel_launch(void* const* d_in, const int* in_sizes, int n_in,
                              void* d_out, int out_size, void* d_ws, size_t ws_size,
                              hipStream_t stream) {
    const float* u     = (const float*)d_in[0];
    const float* v     = (const float*)d_in[1];
    const float* wgt   = (const float*)d_in[2];
    const float* gamma = (const float*)d_in[3];
    const float* beta  = (const float*)d_in[4];
    const float* mean  = (const float*)d_in[5];
    const float* var   = (const float*)d_in[6];
    float* out = (float*)d_out;
    ushort* wf = (ushort*)d_ws;                 // 288 KB of ws for bf16 weight frags

    prep_weights<<<dim3((WFRAGS * 64 + 255) / 256), dim3(256), 0, stream>>>(wgt, wf);
    crossconv_mfma<<<dim3(Wd / 16, Hd / 16, 4), dim3(NTHR), 0, stream>>>(
        u, v, wf, gamma, beta, mean, var, out);
}